// Round 1
// 238.462 us; speedup vs baseline: 1.0807x; 1.0807x over previous
//
#include <hip/hip_runtime.h>
#include <hip/hip_bf16.h>

typedef short v8s __attribute__((ext_vector_type(8)));
typedef float v4f __attribute__((ext_vector_type(4)));

#define LDK 72                    // padded LDS row stride (bf16 elems): 144 B, 16B-aligned rows
#define SCALE_LOG2E 0.18033688f   // (1/sqrt(64)) * log2(e), folded into Q at staging
#define RESCALE_THR 8.0f          // defer-max threshold (T13): P bounded by 2^8, bf16-safe

struct MMRAParams {
    const float* q[4];
    const float* k[4];
    const float* v[4];
    const int*   rg[4];
    const int*   mask;
    float*       out;
};

// Native packed fp32->bf16 (RNE), 1 VALU op for a pair. gfx950-only instruction;
// no builtin exposed, so inline asm (non-volatile: pure, CSE/schedulable).
__device__ __forceinline__ unsigned pkbf(float a, float b) {
    unsigned r;
    asm("v_cvt_pk_bf16_f32 %0, %1, %2" : "=v"(r) : "v"(a), "v"(b));
    return r;   // low = bf16(a), high = bf16(b)
}

__global__ __launch_bounds__(256, 2)
void mmra_attn(MMRAParams P) {
    const int bid = blockIdx.x;       // 512 blocks; bid&7 = b*4+h for XCD L2 locality
    const int h = bid & 3;
    const int b = (bid >> 2) & 1;
    const int n = bid >> 3;           // region 0..63
    const int H0 = ((n >> 4) & 3) << 2;
    const int W0 = ((n >> 2) & 3) << 2;
    const int D0 = (n & 3) << 2;

    const int tid  = threadIdx.x;
    const int wave = tid >> 6;        // q-modality of this wave
    const int lane = tid & 63;
    const int l15  = lane & 15;
    const int quad = lane >> 4;

    __shared__ __align__(16) ushort Klds[64 * LDK];       // [token][c]  (bf16)
    __shared__ __align__(16) ushort Vlds[64 * LDK];       // [c][token]  (bf16, transposed)
    __shared__ __align__(16) ushort Plds[4][64 * LDK];    // per-wave private: 4 P tiles / Q staging

    const int bh_base = (b * 256 + h * 64) * 4096;        // fp32 elem idx base
    const int rgbase  = ((b * 4 + h) * 64 + n) * 4;

    const bool actm[4] = { P.mask[b * 4 + 0] != 0, P.mask[b * 4 + 1] != 0,
                           P.mask[b * 4 + 2] != 0, P.mask[b * 4 + 3] != 0 };

    auto kptr = [&](int m) { return (m == 0) ? P.k[0] : (m == 1) ? P.k[1] : (m == 2) ? P.k[2] : P.k[3]; };
    auto vptr = [&](int m) { return (m == 0) ? P.v[0] : (m == 1) ? P.v[1] : (m == 2) ? P.v[2] : P.v[3]; };
    auto rptr = [&](int m) { return (m == 0) ? P.rg[0] : (m == 1) ? P.rg[1] : (m == 2) ? P.rg[2] : P.rg[3]; };

    // ---------------- chunk prefetch registers ----------------
    float4 pkf[4], pvf[4];
    auto prefetch = [&](int cj) {
        const int mod = cj >> 2, j = cj & 3;
        const int g = rptr(mod)[rgbase + j] & 63;
        const int goff = (((g >> 4) & 3) << 10) + (((g >> 2) & 3) << 6) + ((g & 3) << 2);
        const float* ks = kptr(mod);
        const float* vs = vptr(mod);
        const int off0 = bh_base + lane * 4096 + goff;
        #pragma unroll
        for (int i = 0; i < 4; ++i) {
            const int pq = wave * 4 + i;
            const int off = off0 + (pq >> 2) * 256 + (pq & 3) * 16;
            pkf[i] = *(const float4*)(ks + off);
            pvf[i] = *(const float4*)(vs + off);
        }
    };

    prefetch(0);   // chunk-0 loads overlap Q staging below

    // ------- Q staging: per-wave PRIVATE Plds[wave] (64 rows), ONE drain -------
    // Q pre-scaled by SCALE_LOG2E so S comes out directly in log2 domain.
    v8s qfrag[4][2];
    {
        ushort* qbuf = &Plds[wave][0];
        const float* qsrc = (wave == 0) ? P.q[0] : (wave == 1) ? P.q[1] : (wave == 2) ? P.q[2] : P.q[3];
        #pragma unroll
        for (int rb = 0; rb < 4; ++rb) {          // rb = p (y) coordinate = mt
            #pragma unroll
            for (int i = 0; i < 4; ++i) {         // i = x coordinate; c = lane
                int off = bh_base + lane * 4096 + (H0 + rb) * 256 + (W0 + i) * 16 + D0;
                float4 cv = *(const float4*)(qsrc + off);
                unsigned q01 = pkbf(cv.x * SCALE_LOG2E, cv.y * SCALE_LOG2E);
                unsigned q23 = pkbf(cv.z * SCALE_LOG2E, cv.w * SCALE_LOG2E);
                ushort* qb = &qbuf[(rb * 16 + i * 4) * LDK + lane];
                qb[0 * LDK] = (ushort)q01;
                qb[1 * LDK] = (ushort)(q01 >> 16);   // trunc(lshr) -> ds_write_b16_d16_hi
                qb[2 * LDK] = (ushort)q23;
                qb[3 * LDK] = (ushort)(q23 >> 16);
            }
        }
        __asm__ volatile("s_waitcnt lgkmcnt(0)" ::: "memory");   // wave-local write->read
        #pragma unroll
        for (int rb = 0; rb < 4; ++rb) {
            qfrag[rb][0] = *(const v8s*)&qbuf[(rb * 16 + l15) * LDK + quad * 8];
            qfrag[rb][1] = *(const v8s*)&qbuf[(rb * 16 + l15) * LDK + 32 + quad * 8];
        }
    }

    v4f  oacc[4][4];
    float mrow[4], lrow[4];       // softmax state per mt, indexed by q = l15 (dup across quads)
    #pragma unroll
    for (int mt = 0; mt < 4; ++mt) {
        mrow[mt] = -1e30f; lrow[mt] = 0.f;
        #pragma unroll
        for (int nt = 0; nt < 4; ++nt) oacc[mt][nt] = (v4f){0.f, 0.f, 0.f, 0.f};
    }

    #pragma unroll 1
    for (int cj = 0; cj < 16; ++cj) {             // chunk = (modality, topk-slot)
        const bool act = actm[cj >> 2];           // block-uniform
        if (act) {
            __syncthreads();   // prior chunk's K/V frag reads complete before restage
            #pragma unroll
            for (int i = 0; i < 4; ++i) {
                const int pq = wave * 4 + i;
                unsigned k01 = pkbf(pkf[i].x, pkf[i].y);
                unsigned k23 = pkbf(pkf[i].z, pkf[i].w);
                ushort* kb = &Klds[(pq * 4) * LDK + lane];
                kb[0 * LDK] = (ushort)k01;
                kb[1 * LDK] = (ushort)(k01 >> 16);
                kb[2 * LDK] = (ushort)k23;
                kb[3 * LDK] = (ushort)(k23 >> 16);
                uint2 vv;
                vv.x = pkbf(pvf[i].x, pvf[i].y);
                vv.y = pkbf(pvf[i].z, pvf[i].w);
                *(uint2*)&Vlds[lane * LDK + pq * 4] = vv;   // transposed, packed 8B
            }
        }
        if (cj < 15) prefetch(cj + 1);     // overlaps phases A+B below
        if (!act) continue;                // uniform skip == -inf mask
        __syncthreads();

        // ================= PHASE A: QK^T + softmax + P-writes for ALL mt (no drains) ==========
        {
            v8s kfrag[4][2];
            #pragma unroll
            for (int t = 0; t < 4; ++t) {
                kfrag[t][0] = *(const v8s*)&Klds[(t * 16 + l15) * LDK + quad * 8];
                kfrag[t][1] = *(const v8s*)&Klds[(t * 16 + l15) * LDK + 32 + quad * 8];
            }
            #pragma unroll
            for (int mt = 0; mt < 4; ++mt) {
                // S^T tile: D[m=key][n=q]. sv[nt][r]: key = nt*16+quad*4+r, q = l15.
                float sv[4][4];
                #pragma unroll
                for (int nt = 0; nt < 4; ++nt) {
                    v4f acc = (v4f){0.f, 0.f, 0.f, 0.f};
                    acc = __builtin_amdgcn_mfma_f32_16x16x32_bf16(kfrag[nt][0], qfrag[mt][0], acc, 0, 0, 0);
                    acc = __builtin_amdgcn_mfma_f32_16x16x32_bf16(kfrag[nt][1], qfrag[mt][1], acc, 0, 0, 0);
                    #pragma unroll
                    for (int r = 0; r < 4; ++r) sv[nt][r] = acc[r];
                }
                // column (=q) max: v_max3-friendly tree, then across quads (xor 16, 32)
                float mx;
                {
                    float a0 = fmaxf(fmaxf(sv[0][0], sv[0][1]), sv[0][2]);
                    float a1 = fmaxf(fmaxf(sv[0][3], sv[1][0]), sv[1][1]);
                    float a2 = fmaxf(fmaxf(sv[1][2], sv[1][3]), sv[2][0]);
                    float a3 = fmaxf(fmaxf(sv[2][1], sv[2][2]), sv[2][3]);
                    float a4 = fmaxf(fmaxf(sv[3][0], sv[3][1]), sv[3][2]);
                    mx = fmaxf(fmaxf(fmaxf(a0, a1), a2), fmaxf(fmaxf(a3, a4), sv[3][3]));
                }
                mx = fmaxf(mx, __shfl_xor(mx, 16));
                mx = fmaxf(mx, __shfl_xor(mx, 32));

                // T13 defer-max: only rescale when some row's max grew by > THR.
                // mrow is uniform across quads for a given l15, so the branch is wave-uniform.
                if (!__all(mx - mrow[mt] <= RESCALE_THR)) {
                    const float mnew  = fmaxf(mrow[mt], mx);
                    const float alpha = exp2f(mrow[mt] - mnew);
                    mrow[mt] = mnew;
                    lrow[mt] *= alpha;
                    // rescale O: transpose alpha from q=l15 indexing to O-row (q=quad*4+r) indexing
                    float alpha_row[4];
                    #pragma unroll
                    for (int r = 0; r < 4; ++r)
                        alpha_row[r] = __shfl(alpha, (quad << 4) | (quad * 4 + r));
                    #pragma unroll
                    for (int nt = 0; nt < 4; ++nt)
                        #pragma unroll
                        for (int r = 0; r < 4; ++r) oacc[mt][nt][r] *= alpha_row[r];
                }
                const float mcur = mrow[mt];

                // P = exp2(S - m): packed b64 writes to this wave's mt-th P tile (row=q, col=key)
                float rsum = 0.f;
                #pragma unroll
                for (int nt = 0; nt < 4; ++nt) {
                    float p0 = exp2f(sv[nt][0] - mcur);
                    float p1 = exp2f(sv[nt][1] - mcur);
                    float p2 = exp2f(sv[nt][2] - mcur);
                    float p3 = exp2f(sv[nt][3] - mcur);
                    rsum += (p0 + p1) + (p2 + p3);
                    uint2 pw;
                    pw.x = pkbf(p0, p1);
                    pw.y = pkbf(p2, p3);
                    *(uint2*)&Plds[wave][(mt * 16 + l15) * LDK + nt * 16 + quad * 4] = pw;
                }
                rsum += __shfl_xor(rsum, 16);
                rsum += __shfl_xor(rsum, 32);
                lrow[mt] += rsum;
            }
        }

        // ================= PHASE B: one drain, then all PV MFMAs ==============================
        __asm__ volatile("s_waitcnt lgkmcnt(0)" ::: "memory");   // P writes visible to own wave
        {
            v8s vfrag[4][2];
            #pragma unroll
            for (int t = 0; t < 4; ++t) {
                vfrag[t][0] = *(const v8s*)&Vlds[(t * 16 + l15) * LDK + quad * 8];
                vfrag[t][1] = *(const v8s*)&Vlds[(t * 16 + l15) * LDK + 32 + quad * 8];
            }
            #pragma unroll
            for (int mt = 0; mt < 4; ++mt) {
                v8s pf0 = *(const v8s*)&Plds[wave][(mt * 16 + l15) * LDK + quad * 8];
                v8s pf1 = *(const v8s*)&Plds[wave][(mt * 16 + l15) * LDK + 32 + quad * 8];
                #pragma unroll
                for (int nt = 0; nt < 4; ++nt) {
                    oacc[mt][nt] = __builtin_amdgcn_mfma_f32_16x16x32_bf16(pf0, vfrag[nt][0], oacc[mt][nt], 0, 0, 0);
                    oacc[mt][nt] = __builtin_amdgcn_mfma_f32_16x16x32_bf16(pf1, vfrag[nt][1], oacc[mt][nt], 0, 0, 0);
                }
            }
        }
    }

    // ---------------- epilogue: O /= l (quad-transposed), seq2grid, float4 stores ----------------
    const int obase = (wave * 2 + b) * 1048576 + h * 64 * 4096;
    #pragma unroll
    for (int mt = 0; mt < 4; ++mt) {
        const float invq = 1.0f / lrow[mt];
        float inv_row[4];
        #pragma unroll
        for (int r = 0; r < 4; ++r)
            inv_row[r] = __shfl(invq, (quad << 4) | (quad * 4 + r));
        #pragma unroll
        for (int nt = 0; nt < 4; ++nt) {
            float4 ov;
            ov.x = oacc[mt][nt][0] * inv_row[0];
            ov.y = oacc[mt][nt][1] * inv_row[1];
            ov.z = oacc[mt][nt][2] * inv_row[2];
            ov.w = oacc[mt][nt][3] * inv_row[3];
            int off = obase + (nt * 16 + l15) * 4096 + (H0 + mt) * 256 + (W0 + quad) * 16 + D0;
            *(float4*)(P.out + off) = ov;
        }
    }
}

extern "C" void kernel_launch(void* const* d_in, const int* in_sizes, int n_in,
                              void* d_out, int out_size, void* d_ws, size_t ws_size,
                              hipStream_t stream) {
    (void)in_sizes; (void)n_in; (void)out_size; (void)d_ws; (void)ws_size;
    MMRAParams P;
    P.mask = (const int*)d_in[0];
    for (int i = 0; i < 4; ++i) {
        P.q[i]  = (const float*)d_in[1 + i];
        P.k[i]  = (const float*)d_in[5 + i];
        P.v[i]  = (const float*)d_in[9 + i];
        P.rg[i] = (const int*)d_in[13 + i];
    }
    P.out = (float*)d_out;
    hipLaunchKernelGGL(mmra_attn, dim3(512), dim3(256), 0, stream, P);
}